// Round 7
// baseline (297.544 us; speedup 1.0000x reference)
//
#include <hip/hip_runtime.h>

typedef unsigned short u16;
typedef __attribute__((ext_vector_type(8))) short bf16x8;
typedef __attribute__((ext_vector_type(8))) unsigned short u16x8;
typedef __attribute__((ext_vector_type(4))) float f32x4;

#define AS1 __attribute__((address_space(1)))
#define AS3 __attribute__((address_space(3)))

__device__ __forceinline__ void gld16(const void* g, void* l) {
    __builtin_amdgcn_global_load_lds((const AS1 void*)g, (AS3 void*)l, 16, 0, 0);
}

__device__ __forceinline__ u16 f2bf(float f) {
    unsigned int u = __float_as_uint(f);
    unsigned int r = (u >> 16) & 1u;
    u += 0x7fffu + r;
    return (u16)(u >> 16);
}

__device__ __forceinline__ float gelu_exact(float v) {
    return 0.5f * v * (1.0f + erff(v * 0.70710678118654752f));
}

// ---------------- W1 transpose + cast: W[R][C] f32 -> Wt[C][R] bf16 ----------
__global__ __launch_bounds__(256) void transpose_cast(
    const float* __restrict__ W, u16* __restrict__ Wt, int R, int C) {
    __shared__ float t[32][33];
    const int tx = threadIdx.x & 31, tg = threadIdx.x >> 5;
    const int c0 = blockIdx.x * 32, r0 = blockIdx.y * 32;
#pragma unroll
    for (int i = 0; i < 4; ++i) {
        int rr = tg + i * 8;
        t[rr][tx] = W[(long)(r0 + rr) * C + c0 + tx];
    }
    __syncthreads();
#pragma unroll
    for (int i = 0; i < 4; ++i) {
        int rr = tg + i * 8;
        Wt[(long)(c0 + rr) * R + r0 + tx] = f2bf(t[tx][rr]);
    }
}

// ---------------- TT core contraction ----------------------------------------
__global__ __launch_bounds__(256) void tt_m1_kernel(
    const float* __restrict__ g1, const float* __restrict__ g2,
    float* __restrict__ M1) {
    const int id = blockIdx.x * 256 + threadIdx.x;       // 262144
    const int t = id & 15, q = (id >> 4) & 15, p = (id >> 8) & 7;
    const int j = (id >> 11) & 15, i = id >> 15;
    float acc = 0.f;
#pragma unroll
    for (int s = 0; s < 16; ++s)
        acc += g1[(i * 8 + p) * 16 + s] * g2[((s * 16 + j) * 16 + q) * 16 + t];
    M1[id] = acc;
}

__global__ __launch_bounds__(256) void tt_w2t_kernel(
    const float* __restrict__ M1, const float* __restrict__ g3,
    u16* __restrict__ W2T) {
    const int id = blockIdx.x * 256 + threadIdx.x;       // 2097152
    const int fi = id & 2047, fo = id >> 11;
    const int i = fi >> 8, j = (fi >> 4) & 15, k = fi & 15;
    const int p = fo >> 7, q = (fo >> 3) & 15, u = fo & 7;
    const float* m = &M1[(((i * 16 + j) * 8 + p) * 16 + q) * 16];
    float acc = 0.f;
#pragma unroll
    for (int t = 0; t < 16; ++t)
        acc += m[t] * g3[(t * 16 + k) * 8 + u];
    W2T[id] = f2bf(acc);
}

// ---------------- LayerNorm 1: x f32 -> xln bf16 -----------------------------
__global__ __launch_bounds__(256) void ln1_kernel(
    const float* __restrict__ x, const float* __restrict__ gamma,
    const float* __restrict__ beta, u16* __restrict__ out) {
    const long row = blockIdx.x;
    const int tid = threadIdx.x;
    const float4 v = ((const float4*)(x + row * 1024))[tid];
    float s = v.x + v.y + v.z + v.w;
    float ss = v.x * v.x + v.y * v.y + v.z * v.z + v.w * v.w;
#pragma unroll
    for (int off = 32; off; off >>= 1) {
        s += __shfl_down(s, off, 64);
        ss += __shfl_down(ss, off, 64);
    }
    __shared__ float rs[4], rss[4];
    const int w = tid >> 6, lane = tid & 63;
    if (lane == 0) { rs[w] = s; rss[w] = ss; }
    __syncthreads();
    s = rs[0] + rs[1] + rs[2] + rs[3];
    ss = rss[0] + rss[1] + rss[2] + rss[3];
    const float mu = s * (1.0f / 1024.0f);
    const float var = ss * (1.0f / 1024.0f) - mu * mu;
    const float rstd = rsqrtf(var + 1e-5f);
    const float4 gm = ((const float4*)gamma)[tid];
    const float4 bt = ((const float4*)beta)[tid];
    ushort4 o;
    o.x = f2bf((v.x - mu) * rstd * gm.x + bt.x);
    o.y = f2bf((v.y - mu) * rstd * gm.y + bt.y);
    o.z = f2bf((v.z - mu) * rstd * gm.z + bt.z);
    o.w = f2bf((v.w - mu) * rstd * gm.w + bt.w);
    ((ushort4*)(out + row * 1024))[tid] = o;
}

// ---------------- LayerNorm 2 (in-place): z -> z + LN(z) ---------------------
__global__ __launch_bounds__(256) void ln2_kernel(
    float* __restrict__ z, const float* __restrict__ gamma,
    const float* __restrict__ beta) {
    const long row = blockIdx.x;
    const int tid = threadIdx.x;
    const float4 v = ((const float4*)(z + row * 1024))[tid];
    float s = v.x + v.y + v.z + v.w;
    float ss = v.x * v.x + v.y * v.y + v.z * v.z + v.w * v.w;
#pragma unroll
    for (int off = 32; off; off >>= 1) {
        s += __shfl_down(s, off, 64);
        ss += __shfl_down(ss, off, 64);
    }
    __shared__ float rs[4], rss[4];
    const int w = tid >> 6, lane = tid & 63;
    if (lane == 0) { rs[w] = s; rss[w] = ss; }
    __syncthreads();
    s = rs[0] + rs[1] + rs[2] + rs[3];
    ss = rss[0] + rss[1] + rss[2] + rss[3];
    const float mu = s * (1.0f / 1024.0f);
    const float var = ss * (1.0f / 1024.0f) - mu * mu;
    const float rstd = rsqrtf(var + 1e-5f);
    const float4 gm = ((const float4*)gamma)[tid];
    const float4 bt = ((const float4*)beta)[tid];
    float4 o;
    o.x = v.x + ((v.x - mu) * rstd * gm.x + bt.x);
    o.y = v.y + ((v.y - mu) * rstd * gm.y + bt.y);
    o.z = v.z + ((v.z - mu) * rstd * gm.z + bt.z);
    o.w = v.w + ((v.w - mu) * rstd * gm.w + bt.w);
    ((float4*)(z + row * 1024))[tid] = o;
}

// ---------------- 128x128 GEMM (m97/m103 structure): C = A @ Bt^T ------------
// 256 threads (4 waves 2x2, each 64x64 = 4x4 fragments), BK=32,
// SINGLE-buffered 16 KB LDS, 2 barriers/K-step, 3 blocks/CU for cross-block
// overlap. Conflict-free swizzle byte ^= ((row>>1)&3)<<4 (R5-validated),
// coalesced LDS-transpose epilogue.
// EPI=0: out = bf16(gelu(acc + bias[col]))
// EPI=1: out = f32(acc + bias[col] + resid[row][col])
template <int EPI>
__global__ __launch_bounds__(256, 3) void gemm128(
    const u16* __restrict__ A, const u16* __restrict__ Bt,
    void* __restrict__ outp, const float* __restrict__ bias,
    const float* __restrict__ resid, int M, int N, int K) {
    __shared__ char smem[16896];   // loop: A 8K + B 8K; epilogue: 2*16*132*4
    const int tid = threadIdx.x;
    int b = blockIdx.x;
    const int nwg = gridDim.x;
    if ((nwg & 7) == 0 && nwg >= 8) {   // XCD-aware swizzle (bijective)
        const int per = nwg >> 3;
        b = (b & 7) * per + (b >> 3);
    }
    const int NT = N >> 7;
    const int mt = b / NT, nt = b - mt * NT;
    const long m0 = (long)mt << 7, n0 = (long)nt << 7;

    const int lane = tid & 63, wid = tid >> 6;
    const int wr = wid >> 1, wc = wid & 1;
    const int r = lane & 15, g = lane >> 4;

    // staging: linear LDS dest (gld16: wave-uniform base + lane*16); global
    // source column pre-swizzled with byte ^= ((row>>1)&3)<<4 (row = lin>>6).
    const int lin0 = tid * 16, lin1 = tid * 16 + 4096;
    const int sr0 = lin0 >> 6, sc0 = ((lin0 & 63) ^ (((lin0 >> 7) & 3) << 4)) >> 1;
    const int sr1 = lin1 >> 6, sc1 = ((lin1 & 63) ^ (((lin1 >> 7) & 3) << 4)) >> 1;

    const u16* pA0 = A + (m0 + sr0) * (long)K + sc0;   // rows 0..63
    const u16* pA1 = A + (m0 + sr1) * (long)K + sc1;   // rows 64..127
    const u16* pB0 = Bt + (n0 + sr0) * (long)K + sc0;
    const u16* pB1 = Bt + (n0 + sr1) * (long)K + sc1;

    // frag-read swizzle: per-thread constant (row = 16*i + base + r)
    const int ac = (g * 16) ^ (((r >> 1) & 3) << 4);
    const int arow = wr * 64, brow = wc * 64;

    f32x4 acc[4][4] = {};

    for (int k0 = 0; k0 < K; k0 += 32) {
        gld16(pA0 + k0, smem + lin0);
        gld16(pA1 + k0, smem + lin1);
        gld16(pB0 + k0, smem + 8192 + lin0);
        gld16(pB1 + k0, smem + 8192 + lin1);
        __syncthreads();   // compiler emits vmcnt(0) drain before barrier
        bf16x8 af[4], bf_[4];
#pragma unroll
        for (int i = 0; i < 4; ++i)
            af[i] = *(const bf16x8*)(smem + ((arow + i * 16 + r) * 64 + ac));
#pragma unroll
        for (int j = 0; j < 4; ++j)
            bf_[j] = *(const bf16x8*)(smem + 8192 + ((brow + j * 16 + r) * 64 + ac));
#pragma unroll
        for (int i = 0; i < 4; ++i)
#pragma unroll
            for (int j = 0; j < 4; ++j)
                acc[i][j] = __builtin_amdgcn_mfma_f32_16x16x32_bf16(
                    af[i], bf_[j], acc[i][j], 0, 0, 0);
        __syncthreads();
    }

    // ---- epilogue: LDS-transposed, fully-coalesced C write ----
    float bias_r[4];
#pragma unroll
    for (int j = 0; j < 4; ++j) bias_r[j] = bias[n0 + wc * 64 + j * 16 + r];

    float* eb = (float*)smem;   // double-buffered [2][16][132] f32
#pragma unroll
    for (int s = 0; s < 8; ++s) {       // stripe s = rows s*16 .. s*16+15
        if (wr == (s >> 2)) {
            const int mi = s & 3;
            float* dst = eb + (s & 1) * (16 * 132) + (g * 4) * 132 + wc * 64 + r;
#pragma unroll
            for (int j = 0; j < 4; ++j)
#pragma unroll
                for (int q = 0; q < 4; ++q)
                    dst[q * 132 + j * 16] = acc[mi][j][q] + bias_r[j];
        }
        __syncthreads();
        const float* srcb = eb + (s & 1) * (16 * 132);
        const int flat = tid * 8;
        const int rr = flat >> 7, cc = flat & 127;
        const float4 v0 = *(const float4*)(srcb + rr * 132 + cc);
        const float4 v1 = *(const float4*)(srcb + rr * 132 + cc + 4);
        const long grow = m0 + s * 16 + rr;
        const long gcol = n0 + cc;
        if (EPI == 0) {
            u16x8 o;
            o[0] = f2bf(gelu_exact(v0.x)); o[1] = f2bf(gelu_exact(v0.y));
            o[2] = f2bf(gelu_exact(v0.z)); o[3] = f2bf(gelu_exact(v0.w));
            o[4] = f2bf(gelu_exact(v1.x)); o[5] = f2bf(gelu_exact(v1.y));
            o[6] = f2bf(gelu_exact(v1.z)); o[7] = f2bf(gelu_exact(v1.w));
            *(u16x8*)((u16*)outp + grow * N + gcol) = o;
        } else {
            const float4 r0 = *(const float4*)(resid + grow * N + gcol);
            const float4 r1 = *(const float4*)(resid + grow * N + gcol + 4);
            float4 o0, o1;
            o0.x = v0.x + r0.x; o0.y = v0.y + r0.y;
            o0.z = v0.z + r0.z; o0.w = v0.w + r0.w;
            o1.x = v1.x + r1.x; o1.y = v1.y + r1.y;
            o1.z = v1.z + r1.z; o1.w = v1.w + r1.w;
            *(float4*)((float*)outp + grow * N + gcol) = o0;
            *(float4*)((float*)outp + grow * N + gcol + 4) = o1;
        }
    }
}

extern "C" void kernel_launch(void* const* d_in, const int* in_sizes, int n_in,
                              void* d_out, int out_size, void* d_ws, size_t ws_size,
                              hipStream_t stream) {
    const float* x      = (const float*)d_in[0];
    const float* gamma1 = (const float*)d_in[1];
    const float* beta1  = (const float*)d_in[2];
    const float* W1     = (const float*)d_in[3];
    const float* b1     = (const float*)d_in[4];
    const float* g1     = (const float*)d_in[5];
    const float* g2     = (const float*)d_in[6];
    const float* g3     = (const float*)d_in[7];
    const float* ttb    = (const float*)d_in[8];
    const float* gamma2 = (const float*)d_in[9];
    const float* beta2  = (const float*)d_in[10];

    const int ROWS = 16384, D = 1024, F = 2048;

    char* ws = (char*)d_ws;
    u16* W1T = (u16*)ws;                                  // F*D bf16 = 4 MiB
    u16* W2T = (u16*)(ws + (size_t)F * D * 2);            // D*F bf16 = 4 MiB
    float* M1 = (float*)(ws + (size_t)F * D * 4);         // 262144 f32 = 1 MiB
    char* dyn = ws + (size_t)F * D * 4 + 262144 * 4;
    const size_t fixed = (size_t)(dyn - ws);

    int Rc = ROWS;  // rows per chunk; shrink if workspace is small
    while (Rc > 256 && fixed + (size_t)Rc * 6144 > ws_size) Rc >>= 1;

    u16* xln = (u16*)dyn;                                 // Rc*1024 bf16
    u16* h   = (u16*)(dyn + (size_t)Rc * D * 2);          // Rc*2048 bf16

    transpose_cast<<<dim3(F / 32, D / 32), 256, 0, stream>>>(W1, W1T, D, F);
    tt_m1_kernel<<<262144 / 256, 256, 0, stream>>>(g1, g2, M1);
    tt_w2t_kernel<<<(D * F) / 256, 256, 0, stream>>>(M1, g3, W2T);

    float* out = (float*)d_out;
    for (int r0 = 0; r0 < ROWS; r0 += Rc) {
        ln1_kernel<<<Rc, 256, 0, stream>>>(x + (long)r0 * D, gamma1, beta1, xln);
        gemm128<0><<<(Rc / 128) * (F / 128), 256, 0, stream>>>(
            xln, W1T, h, b1, nullptr, Rc, F, D);
        gemm128<1><<<(Rc / 128) * (D / 128), 256, 0, stream>>>(
            h, W2T, out + (long)r0 * D, ttb, x + (long)r0 * D, Rc, D, F);
    }
    ln2_kernel<<<ROWS, 256, 0, stream>>>(out, gamma2, beta2);
}

// Round 8
// 280.625 us; speedup vs baseline: 1.0603x; 1.0603x over previous
//
#include <hip/hip_runtime.h>

typedef unsigned short u16;
typedef __attribute__((ext_vector_type(8))) short bf16x8;
typedef __attribute__((ext_vector_type(8))) unsigned short u16x8;
typedef __attribute__((ext_vector_type(4))) float f32x4;

#define AS1 __attribute__((address_space(1)))
#define AS3 __attribute__((address_space(3)))

__device__ __forceinline__ void gld16(const void* g, void* l) {
    __builtin_amdgcn_global_load_lds((const AS1 void*)g, (AS3 void*)l, 16, 0, 0);
}

__device__ __forceinline__ u16 f2bf(float f) {
    unsigned int u = __float_as_uint(f);
    unsigned int r = (u >> 16) & 1u;
    u += 0x7fffu + r;
    return (u16)(u >> 16);
}

__device__ __forceinline__ float gelu_exact(float v) {
    return 0.5f * v * (1.0f + erff(v * 0.70710678118654752f));
}

// ---------------- W1 transpose + cast: W[R][C] f32 -> Wt[C][R] bf16 ----------
__global__ __launch_bounds__(256) void transpose_cast(
    const float* __restrict__ W, u16* __restrict__ Wt, int R, int C) {
    __shared__ float t[32][33];
    const int tx = threadIdx.x & 31, tg = threadIdx.x >> 5;
    const int c0 = blockIdx.x * 32, r0 = blockIdx.y * 32;
#pragma unroll
    for (int i = 0; i < 4; ++i) {
        int rr = tg + i * 8;
        t[rr][tx] = W[(long)(r0 + rr) * C + c0 + tx];
    }
    __syncthreads();
#pragma unroll
    for (int i = 0; i < 4; ++i) {
        int rr = tg + i * 8;
        Wt[(long)(c0 + rr) * R + r0 + tx] = f2bf(t[tx][rr]);
    }
}

// ---------------- TT core contraction ----------------------------------------
__global__ __launch_bounds__(256) void tt_m1_kernel(
    const float* __restrict__ g1, const float* __restrict__ g2,
    float* __restrict__ M1) {
    const int id = blockIdx.x * 256 + threadIdx.x;       // 262144
    const int t = id & 15, q = (id >> 4) & 15, p = (id >> 8) & 7;
    const int j = (id >> 11) & 15, i = id >> 15;
    float acc = 0.f;
#pragma unroll
    for (int s = 0; s < 16; ++s)
        acc += g1[(i * 8 + p) * 16 + s] * g2[((s * 16 + j) * 16 + q) * 16 + t];
    M1[id] = acc;
}

__global__ __launch_bounds__(256) void tt_w2t_kernel(
    const float* __restrict__ M1, const float* __restrict__ g3,
    u16* __restrict__ W2T) {
    const int id = blockIdx.x * 256 + threadIdx.x;       // 2097152
    const int fi = id & 2047, fo = id >> 11;
    const int i = fi >> 8, j = (fi >> 4) & 15, k = fi & 15;
    const int p = fo >> 7, q = (fo >> 3) & 15, u = fo & 7;
    const float* m = &M1[(((i * 16 + j) * 8 + p) * 16 + q) * 16];
    float acc = 0.f;
#pragma unroll
    for (int t = 0; t < 16; ++t)
        acc += m[t] * g3[(t * 16 + k) * 8 + u];
    W2T[id] = f2bf(acc);
}

// ---------------- LayerNorm 1: x f32 -> xln bf16 -----------------------------
__global__ __launch_bounds__(256) void ln1_kernel(
    const float* __restrict__ x, const float* __restrict__ gamma,
    const float* __restrict__ beta, u16* __restrict__ out) {
    const long row = blockIdx.x;
    const int tid = threadIdx.x;
    const float4 v = ((const float4*)(x + row * 1024))[tid];
    float s = v.x + v.y + v.z + v.w;
    float ss = v.x * v.x + v.y * v.y + v.z * v.z + v.w * v.w;
#pragma unroll
    for (int off = 32; off; off >>= 1) {
        s += __shfl_down(s, off, 64);
        ss += __shfl_down(ss, off, 64);
    }
    __shared__ float rs[4], rss[4];
    const int w = tid >> 6, lane = tid & 63;
    if (lane == 0) { rs[w] = s; rss[w] = ss; }
    __syncthreads();
    s = rs[0] + rs[1] + rs[2] + rs[3];
    ss = rss[0] + rss[1] + rss[2] + rss[3];
    const float mu = s * (1.0f / 1024.0f);
    const float var = ss * (1.0f / 1024.0f) - mu * mu;
    const float rstd = rsqrtf(var + 1e-5f);
    const float4 gm = ((const float4*)gamma)[tid];
    const float4 bt = ((const float4*)beta)[tid];
    ushort4 o;
    o.x = f2bf((v.x - mu) * rstd * gm.x + bt.x);
    o.y = f2bf((v.y - mu) * rstd * gm.y + bt.y);
    o.z = f2bf((v.z - mu) * rstd * gm.z + bt.z);
    o.w = f2bf((v.w - mu) * rstd * gm.w + bt.w);
    ((ushort4*)(out + row * 1024))[tid] = o;
}

// ---------------- LayerNorm 2 (in-place): z -> z + LN(z) ---------------------
__global__ __launch_bounds__(256) void ln2_kernel(
    float* __restrict__ z, const float* __restrict__ gamma,
    const float* __restrict__ beta) {
    const long row = blockIdx.x;
    const int tid = threadIdx.x;
    const float4 v = ((const float4*)(z + row * 1024))[tid];
    float s = v.x + v.y + v.z + v.w;
    float ss = v.x * v.x + v.y * v.y + v.z * v.z + v.w * v.w;
#pragma unroll
    for (int off = 32; off; off >>= 1) {
        s += __shfl_down(s, off, 64);
        ss += __shfl_down(ss, off, 64);
    }
    __shared__ float rs[4], rss[4];
    const int w = tid >> 6, lane = tid & 63;
    if (lane == 0) { rs[w] = s; rss[w] = ss; }
    __syncthreads();
    s = rs[0] + rs[1] + rs[2] + rs[3];
    ss = rss[0] + rss[1] + rss[2] + rss[3];
    const float mu = s * (1.0f / 1024.0f);
    const float var = ss * (1.0f / 1024.0f) - mu * mu;
    const float rstd = rsqrtf(var + 1e-5f);
    const float4 gm = ((const float4*)gamma)[tid];
    const float4 bt = ((const float4*)beta)[tid];
    float4 o;
    o.x = v.x + ((v.x - mu) * rstd * gm.x + bt.x);
    o.y = v.y + ((v.y - mu) * rstd * gm.y + bt.y);
    o.z = v.z + ((v.z - mu) * rstd * gm.z + bt.z);
    o.w = v.w + ((v.w - mu) * rstd * gm.w + bt.w);
    ((float4*)(z + row * 1024))[tid] = o;
}

// ---------------- 128x128 GEMM, BK=64: C = A @ Bt^T --------------------------
// m97-class structure, BK doubled: 256 threads (4 waves 2x2, 64x64/wave),
// single-buffered 32 KB LDS, 2 barriers per K-step of 64, 4 blocks/CU.
// Per iter/wave: 32 MFMA (2 k-slices of 16) -- halves latency-exposed iters.
// Swizzle: byte ^= (row&7)<<4 on 128 B rows (R6-validated: 0 conflicts),
// both staging source and frag reads. Coalesced LDS-transpose epilogue.
// EPI=0: out = bf16(gelu(acc + bias[col]))
// EPI=1: out = f32(acc + bias[col] + resid[row][col])
template <int EPI>
__global__ __launch_bounds__(256, 4) void gemm128(
    const u16* __restrict__ A, const u16* __restrict__ Bt,
    void* __restrict__ outp, const float* __restrict__ bias,
    const float* __restrict__ resid, int M, int N, int K) {
    __shared__ char smem[32768];   // loop: A 16K + B 16K; epilogue uses 16.5K
    const int tid = threadIdx.x;
    int b = blockIdx.x;
    const int nwg = gridDim.x;
    if ((nwg & 7) == 0 && nwg >= 8) {   // XCD-aware swizzle (bijective)
        const int per = nwg >> 3;
        b = (b & 7) * per + (b >> 3);
    }
    const int NT = N >> 7;
    const int mt = b / NT, nt = b - mt * NT;
    const long m0 = (long)mt << 7, n0 = (long)nt << 7;

    const int lane = tid & 63, wid = tid >> 6;
    const int wr = wid >> 1, wc = wid & 1;
    const int r = lane & 15, g = lane >> 4;

    // staging: linear LDS dest; rows are 128 B; all 4 quarters share one
    // per-thread source column because q*4096 is 0 mod 128 and 32q is 0 mod 8.
    const int lo = tid * 16;
    const int srow = tid >> 3;                                    // 0..31
    const int sc = ((lo & 127) ^ ((srow & 7) << 4)) >> 1;         // elements
    const u16* pA = A + (m0 + srow) * (long)K + sc;
    const u16* pB = Bt + (n0 + srow) * (long)K + sc;

    // frag-read swizzle: per-thread constant; ks1 (+64) XORed as a whole
    const int sx = (r & 7) << 4;
    const int ac0 = (g * 16) ^ sx;
    const int ac1 = (g * 16 + 64) ^ sx;
    const int arow = wr * 64, brow = wc * 64;

    f32x4 acc[4][4] = {};

    for (int k0 = 0; k0 < K; k0 += 64) {
#pragma unroll
        for (int q = 0; q < 4; ++q) {
            gld16(pA + (long)(q * 32) * K + k0, smem + q * 4096 + lo);
            gld16(pB + (long)(q * 32) * K + k0, smem + 16384 + q * 4096 + lo);
        }
        __syncthreads();   // compiler emits vmcnt(0) drain before barrier
        bf16x8 af[4], bf_[4];
        // ---- k-slice 0 ----
#pragma unroll
        for (int i = 0; i < 4; ++i)
            af[i] = *(const bf16x8*)(smem + ((arow + i * 16 + r) * 128 + ac0));
#pragma unroll
        for (int j = 0; j < 4; ++j)
            bf_[j] = *(const bf16x8*)(smem + 16384 + ((brow + j * 16 + r) * 128 + ac0));
#pragma unroll
        for (int i = 0; i < 4; ++i)
#pragma unroll
            for (int j = 0; j < 4; ++j)
                acc[i][j] = __builtin_amdgcn_mfma_f32_16x16x32_bf16(
                    af[i], bf_[j], acc[i][j], 0, 0, 0);
        // ---- k-slice 1 ----
#pragma unroll
        for (int i = 0; i < 4; ++i)
            af[i] = *(const bf16x8*)(smem + ((arow + i * 16 + r) * 128 + ac1));
#pragma unroll
        for (int j = 0; j < 4; ++j)
            bf_[j] = *(const bf16x8*)(smem + 16384 + ((brow + j * 16 + r) * 128 + ac1));
#pragma unroll
        for (int i = 0; i < 4; ++i)
#pragma unroll
            for (int j = 0; j < 4; ++j)
                acc[i][j] = __builtin_amdgcn_mfma_f32_16x16x32_bf16(
                    af[i], bf_[j], acc[i][j], 0, 0, 0);
        __syncthreads();
    }

    // ---- epilogue: LDS-transposed, fully-coalesced C write ----
    float bias_r[4];
#pragma unroll
    for (int j = 0; j < 4; ++j) bias_r[j] = bias[n0 + wc * 64 + j * 16 + r];

    float* eb = (float*)smem;   // double-buffered [2][16][132] f32
#pragma unroll
    for (int s = 0; s < 8; ++s) {       // stripe s = rows s*16 .. s*16+15
        if (wr == (s >> 2)) {
            const int mi = s & 3;
            float* dst = eb + (s & 1) * (16 * 132) + (g * 4) * 132 + wc * 64 + r;
#pragma unroll
            for (int j = 0; j < 4; ++j)
#pragma unroll
                for (int q = 0; q < 4; ++q)
                    dst[q * 132 + j * 16] = acc[mi][j][q] + bias_r[j];
        }
        __syncthreads();
        const float* srcb = eb + (s & 1) * (16 * 132);
        const int flat = tid * 8;
        const int rr = flat >> 7, cc = flat & 127;
        const float4 v0 = *(const float4*)(srcb + rr * 132 + cc);
        const float4 v1 = *(const float4*)(srcb + rr * 132 + cc + 4);
        const long grow = m0 + s * 16 + rr;
        const long gcol = n0 + cc;
        if (EPI == 0) {
            u16x8 o;
            o[0] = f2bf(gelu_exact(v0.x)); o[1] = f2bf(gelu_exact(v0.y));
            o[2] = f2bf(gelu_exact(v0.z)); o[3] = f2bf(gelu_exact(v0.w));
            o[4] = f2bf(gelu_exact(v1.x)); o[5] = f2bf(gelu_exact(v1.y));
            o[6] = f2bf(gelu_exact(v1.z)); o[7] = f2bf(gelu_exact(v1.w));
            *(u16x8*)((u16*)outp + grow * N + gcol) = o;
        } else {
            const float4 r0 = *(const float4*)(resid + grow * N + gcol);
            const float4 r1 = *(const float4*)(resid + grow * N + gcol + 4);
            float4 o0, o1;
            o0.x = v0.x + r0.x; o0.y = v0.y + r0.y;
            o0.z = v0.z + r0.z; o0.w = v0.w + r0.w;
            o1.x = v1.x + r1.x; o1.y = v1.y + r1.y;
            o1.z = v1.z + r1.z; o1.w = v1.w + r1.w;
            *(float4*)((float*)outp + grow * N + gcol) = o0;
            *(float4*)((float*)outp + grow * N + gcol + 4) = o1;
        }
    }
}

extern "C" void kernel_launch(void* const* d_in, const int* in_sizes, int n_in,
                              void* d_out, int out_size, void* d_ws, size_t ws_size,
                              hipStream_t stream) {
    const float* x      = (const float*)d_in[0];
    const float* gamma1 = (const float*)d_in[1];
    const float* beta1  = (const float*)d_in[2];
    const float* W1     = (const float*)d_in[3];
    const float* b1     = (const float*)d_in[4];
    const float* g1     = (const float*)d_in[5];
    const float* g2     = (const float*)d_in[6];
    const float* g3     = (const float*)d_in[7];
    const float* ttb    = (const float*)d_in[8];
    const float* gamma2 = (const float*)d_in[9];
    const float* beta2  = (const float*)d_in[10];

    const int ROWS = 16384, D = 1024, F = 2048;

    char* ws = (char*)d_ws;
    u16* W1T = (u16*)ws;                                  // F*D bf16 = 4 MiB
    u16* W2T = (u16*)(ws + (size_t)F * D * 2);            // D*F bf16 = 4 MiB
    float* M1 = (float*)(ws + (size_t)F * D * 4);         // 262144 f32 = 1 MiB
    char* dyn = ws + (size_t)F * D * 4 + 262144 * 4;
    const size_t fixed = (size_t)(dyn - ws);

    int Rc = ROWS;  // rows per chunk; shrink if workspace is small
    while (Rc > 256 && fixed + (size_t)Rc * 6144 > ws_size) Rc >>= 1;

    u16* xln = (u16*)dyn;                                 // Rc*1024 bf16
    u16* h   = (u16*)(dyn + (size_t)Rc * D * 2);          // Rc*2048 bf16

    transpose_cast<<<dim3(F / 32, D / 32), 256, 0, stream>>>(W1, W1T, D, F);
    tt_m1_kernel<<<262144 / 256, 256, 0, stream>>>(g1, g2, M1);
    tt_w2t_kernel<<<(D * F) / 256, 256, 0, stream>>>(M1, g3, W2T);

    float* out = (float*)d_out;
    for (int r0 = 0; r0 < ROWS; r0 += Rc) {
        ln1_kernel<<<Rc, 256, 0, stream>>>(x + (long)r0 * D, gamma1, beta1, xln);
        gemm128<0><<<(Rc / 128) * (F / 128), 256, 0, stream>>>(
            xln, W1T, h, b1, nullptr, Rc, F, D);
        gemm128<1><<<(Rc / 128) * (D / 128), 256, 0, stream>>>(
            h, W2T, out + (long)r0 * D, ttb, x + (long)r0 * D, Rc, D, F);
    }
    ln2_kernel<<<ROWS, 256, 0, stream>>>(out, gamma2, beta2);
}